// Round 13
// baseline (321.012 us; speedup 1.0000x reference)
//
#include <hip/hip_runtime.h>
#include <hip/hip_bf16.h>
#include <math.h>

#define NN 50000
#define NE 600000
#define CC 128
#define NL 3
#define NRG (NN / 16)      // 3125 row-groups
#define C_RG 4             // row-groups per conv wave
#define G_RG 4             // row-groups per gru wave
#define SCAN_B 196         // ceil(NN/256)

typedef __attribute__((ext_vector_type(8))) short bf16x8;
typedef __attribute__((ext_vector_type(4))) float f32x4;
typedef unsigned short ushort_t;
typedef unsigned int uint_t;

__device__ inline ushort_t f2bf(float f) {
    __hip_bfloat16 b = __float2bfloat16(f);
    return *reinterpret_cast<ushort_t*>(&b);
}
__device__ inline float bf2f(ushort_t u) {
    return __uint_as_float(((uint_t)u) << 16);
}
__device__ inline float fsig(float x) {
    return __builtin_amdgcn_rcpf(1.f + __builtin_amdgcn_exp2f(-1.44269504f * x));
}
__device__ inline float ftanh(float x) {
    float e = __builtin_amdgcn_exp2f(2.88539008f * fabsf(x));
    float t = 1.f - 2.f * __builtin_amdgcn_rcpf(e + 1.f);
    return copysignf(t, x);
}

// ---------------- merged prep: cvt + all weight packs + deg/cnt zero ----------------
__global__ __launch_bounds__(256) void k_prep(const float* __restrict__ x,
                                              ushort_t* __restrict__ h_bf,
                                              const float* __restrict__ wih,
                                              const float* __restrict__ whh,
                                              const float* __restrict__ cw,
                                              const float* __restrict__ w0,
                                              const float* __restrict__ w1,
                                              const float* __restrict__ w2,
                                              const float* __restrict__ w3,
                                              ushort_t* __restrict__ wx_pk,
                                              ushort_t* __restrict__ wh_pk,
                                              ushort_t* __restrict__ cw_pk,
                                              ushort_t* __restrict__ wm_pk,
                                              int* __restrict__ degcnt) {
    int bid = blockIdx.x;
    int t = threadIdx.x;
    if (bid < 6250) {
        size_t i = (size_t)bid * 256 + t;
        float4 v = ((const float4*)x)[i];
        ushort4 u;
        u.x = f2bf(v.x); u.y = f2bf(v.y); u.z = f2bf(v.z); u.w = f2bf(v.w);
        ((ushort4*)h_bf)[i] = u;
        return;
    }
    int bb = bid - 6250;
    if (bb < 384) {
        const float* W = (bb < 192) ? wih : whh;
        ushort_t* pk = (bb < 192) ? wx_pk : wh_pk;
        int tid = ((bb < 192) ? bb : bb - 192) * 256 + t;    // 49152
        int e = tid & 7;
        int l = (tid >> 3) & 63;
        int s = (tid >> 9) & 3;
        int rest = tid >> 11;                // c0*3+g
        int g = rest % 3, c0 = rest / 3;
        int row = g * 128 + c0 * 16 + (l & 15);
        int col = s * 32 + (l >> 4) * 8 + e;
        pk[tid] = f2bf(W[row * 128 + col]);
        return;
    }
    bb -= 384;
    if (bb < 192) {
        int tid = bb * 256 + t;              // 49152
        int e = tid & 7;
        int l = (tid >> 3) & 63;
        int s = (tid >> 9) & 3;
        int rest = tid >> 11;                // layer*8 + c0
        int c0 = rest & 7, layer = rest >> 3;
        int c = c0 * 16 + (l & 15);
        int k = s * 32 + (l >> 4) * 8 + e;
        cw_pk[tid] = f2bf(cw[layer * 16384 + k * 128 + c]);
        return;
    }
    bb -= 192;
    if (bb < 26) {
        int tid = bb * 256 + t;              // 6656
        if (tid >= 6656) return;
        int e = tid & 7;
        int l = (tid >> 3) & 63;
        int lr = l & 15, lg = l >> 4;
        if (tid < 4096) {
            int s = (tid >> 9) & 3;
            int c0 = tid >> 11;
            wm_pk[tid] = f2bf(w0[(c0 * 16 + lr) * 128 + s * 32 + lg * 8 + e]);
        } else if (tid < 5120) {
            int c0 = (tid - 4096) >> 9;
            wm_pk[tid] = f2bf(w1[(c0 * 16 + lr) * 32 + lg * 8 + e]);
        } else if (tid < 6144) {
            int c0 = (tid - 5120) >> 9;
            wm_pk[tid] = f2bf(w2[(c0 * 16 + lr) * 32 + lg * 8 + e]);
        } else {
            wm_pk[tid] = (lr < 7) ? f2bf(w3[lr * 32 + lg * 8 + e]) : (ushort_t)0;
        }
        return;
    }
    bb -= 26;
    {   // zero deg+cnt: 391 blocks over 2*NN ints
        int i = bb * 256 + t;
        if (i < 2 * NN) degcnt[i] = 0;
    }
}

// ---------------- count: int4-vectorized histogram ----------------
__global__ __launch_bounds__(256) void k_count(const int* __restrict__ dst,
                                               int* __restrict__ deg) {
    int c = blockIdx.x * 256 + threadIdx.x;      // over NE/4 int4
    if (c >= NE / 4) return;
    int4 d4 = ((const int4*)dst)[c];
    atomicAdd(&deg[d4.x], 1);
    atomicAdd(&deg[d4.y], 1);
    atomicAdd(&deg[d4.z], 1);
    atomicAdd(&deg[d4.w], 1);
}

__global__ __launch_bounds__(256) void k_scan1(const int* __restrict__ deg,
                                               int* __restrict__ off,
                                               int* __restrict__ bsum) {
    __shared__ int sm[256];
    int t = threadIdx.x, i = blockIdx.x * 256 + t;
    int v = (i < NN) ? deg[i] : 0;
    sm[t] = v;
    __syncthreads();
#pragma unroll
    for (int ofs = 1; ofs < 256; ofs <<= 1) {
        int u = (t >= ofs) ? sm[t - ofs] : 0;
        __syncthreads();
        sm[t] += u;
        __syncthreads();
    }
    if (i < NN) off[i] = sm[t] - v;
    if (t == 255) bsum[blockIdx.x] = sm[255];
}

__global__ __launch_bounds__(256) void k_scan2(const int* __restrict__ bsum,
                                               int* __restrict__ bofs,
                                               int* __restrict__ off) {
    __shared__ int sm[256];
    int t = threadIdx.x;
    int v = (t < SCAN_B) ? bsum[t] : 0;
    sm[t] = v;
    __syncthreads();
#pragma unroll
    for (int ofs = 1; ofs < 256; ofs <<= 1) {
        int u = (t >= ofs) ? sm[t - ofs] : 0;
        __syncthreads();
        sm[t] += u;
        __syncthreads();
    }
    if (t < SCAN_B) bofs[t] = sm[t] - v;
    if (t == 255) off[NN] = sm[255];
}

// ---------------- fill: atomic per-node cursor, one 8B packed store per edge ----------------
__global__ __launch_bounds__(256) void k_fill(const int* __restrict__ src,
                                              const int* __restrict__ dst,
                                              const float* __restrict__ ew,
                                              const int* __restrict__ off_p,
                                              const int* __restrict__ bofs,
                                              int* __restrict__ cnt,
                                              uint2* __restrict__ e_pair) {
    int e = blockIdx.x * 256 + threadIdx.x;
    if (e >= NE) return;
    int d = dst[e];
    int p = off_p[d] + bofs[d >> 8] + atomicAdd(&cnt[d], 1);
    uint2 pr;
    pr.x = (uint_t)src[e];
    pr.y = __float_as_uint(ew[e]);
    e_pair[p] = pr;
}

// ---------------- m_bf = bf16( h_bf @ W ), weight-resident waves ----------------
__global__ __launch_bounds__(256, 2) void k_conv(const ushort_t* __restrict__ h_bf,
                                                 const ushort_t* __restrict__ cw_pk,
                                                 ushort_t* __restrict__ m_bf) {
    int wid = (blockIdx.x * 256 + threadIdx.x) >> 6;
    int l = threadIdx.x & 63;
    int lr = l & 15, lg = l >> 4;
    int c0g = wid & 3;
    int chunk = wid >> 2;

    bf16x8 B[2][4];
    {
        const bf16x8* pw = (const bf16x8*)cw_pk;
#pragma unroll
        for (int p = 0; p < 2; p++)
#pragma unroll
            for (int s = 0; s < 4; s++)
                B[p][s] = pw[(size_t)(((c0g + 4 * p) * 4 + s) * 64) + l];
    }
    int c_lo = c0g * 16 + lr;

    for (int it = 0; it < C_RG; it++) {
        int rg = chunk * C_RG + it;
        if (rg >= NRG) break;
        int n0 = rg * 16;
        const short* ap = (const short*)h_bf + (size_t)(n0 + lr) * CC + lg * 8;
        bf16x8 a[4];
#pragma unroll
        for (int s = 0; s < 4; s++) a[s] = *(const bf16x8*)(ap + s * 32);
        f32x4 acc0 = {0.f,0.f,0.f,0.f}, acc1 = {0.f,0.f,0.f,0.f};
#pragma unroll
        for (int s = 0; s < 4; s++) {
            acc0 = __builtin_amdgcn_mfma_f32_16x16x32_bf16(a[s], B[0][s], acc0, 0, 0, 0);
            acc1 = __builtin_amdgcn_mfma_f32_16x16x32_bf16(a[s], B[1][s], acc1, 0, 0, 0);
        }
#pragma unroll
        for (int j = 0; j < 4; j++) {
            size_t row = (size_t)(n0 + lg * 4 + j) * CC;
            m_bf[row + c_lo] = f2bf(acc0[j]);
            m_bf[row + c_lo + 64] = f2bf(acc1[j]);
        }
    }
}

// ---------------- agg: halves over edges, 8 gathers in flight ----------------
__global__ __launch_bounds__(256) void k_agg(const int* __restrict__ off_p,
                                             const int* __restrict__ bofs,
                                             const uint2* __restrict__ e_pair,
                                             const ushort_t* __restrict__ m_bf,
                                             ushort_t* __restrict__ agg_bf) {
    int node = blockIdx.x * 4 + (threadIdx.x >> 6);
    int l = threadIdx.x & 63;
    int half = l >> 5, sl = l & 31;
    if (node >= NN) return;
    int b = off_p[node] + bofs[node >> 8];
    int e = (node == NN - 1) ? off_p[NN]
                             : off_p[node + 1] + bofs[(node + 1) >> 8];
    const uint2* m2 = (const uint2*)m_bf;   // row = 32 x uint2
    float a0 = 0.f, a1 = 0.f, a2 = 0.f, a3 = 0.f;
    int i = b;
    for (; i + 8 <= e; i += 8) {
        uint2 p0 = e_pair[i + half];
        uint2 p1 = e_pair[i + 2 + half];
        uint2 p2 = e_pair[i + 4 + half];
        uint2 p3 = e_pair[i + 6 + half];
        uint2 v0 = m2[(size_t)p0.x * 32 + sl];
        uint2 v1 = m2[(size_t)p1.x * 32 + sl];
        uint2 v2 = m2[(size_t)p2.x * 32 + sl];
        uint2 v3 = m2[(size_t)p3.x * 32 + sl];
        float w0 = __uint_as_float(p0.y), w1 = __uint_as_float(p1.y);
        float w2 = __uint_as_float(p2.y), w3 = __uint_as_float(p3.y);
        a0 += w0 * bf2f((ushort_t)(v0.x & 0xffffu)) + w1 * bf2f((ushort_t)(v1.x & 0xffffu))
            + w2 * bf2f((ushort_t)(v2.x & 0xffffu)) + w3 * bf2f((ushort_t)(v3.x & 0xffffu));
        a1 += w0 * bf2f((ushort_t)(v0.x >> 16))     + w1 * bf2f((ushort_t)(v1.x >> 16))
            + w2 * bf2f((ushort_t)(v2.x >> 16))     + w3 * bf2f((ushort_t)(v3.x >> 16));
        a2 += w0 * bf2f((ushort_t)(v0.y & 0xffffu)) + w1 * bf2f((ushort_t)(v1.y & 0xffffu))
            + w2 * bf2f((ushort_t)(v2.y & 0xffffu)) + w3 * bf2f((ushort_t)(v3.y & 0xffffu));
        a3 += w0 * bf2f((ushort_t)(v0.y >> 16))     + w1 * bf2f((ushort_t)(v1.y >> 16))
            + w2 * bf2f((ushort_t)(v2.y >> 16))     + w3 * bf2f((ushort_t)(v3.y >> 16));
    }
    for (; i + 4 <= e; i += 4) {
        uint2 p0 = e_pair[i + half];
        uint2 p1 = e_pair[i + 2 + half];
        uint2 v0 = m2[(size_t)p0.x * 32 + sl];
        uint2 v1 = m2[(size_t)p1.x * 32 + sl];
        float w0 = __uint_as_float(p0.y), w1 = __uint_as_float(p1.y);
        a0 += w0 * bf2f((ushort_t)(v0.x & 0xffffu)) + w1 * bf2f((ushort_t)(v1.x & 0xffffu));
        a1 += w0 * bf2f((ushort_t)(v0.x >> 16))     + w1 * bf2f((ushort_t)(v1.x >> 16));
        a2 += w0 * bf2f((ushort_t)(v0.y & 0xffffu)) + w1 * bf2f((ushort_t)(v1.y & 0xffffu));
        a3 += w0 * bf2f((ushort_t)(v0.y >> 16))     + w1 * bf2f((ushort_t)(v1.y >> 16));
    }
    for (; i < e; i += 2) {
        int idx = i + half;
        uint2 pr = (idx < e) ? e_pair[idx] : make_uint2(0u, 0u);
        uint2 v = m2[(size_t)pr.x * 32 + sl];
        float w = __uint_as_float(pr.y);
        a0 += w * bf2f((ushort_t)(v.x & 0xffffu));
        a1 += w * bf2f((ushort_t)(v.x >> 16));
        a2 += w * bf2f((ushort_t)(v.y & 0xffffu));
        a3 += w * bf2f((ushort_t)(v.y >> 16));
    }
    a0 += __shfl_xor(a0, 32);
    a1 += __shfl_xor(a1, 32);
    a2 += __shfl_xor(a2, 32);
    a3 += __shfl_xor(a3, 32);
    if (half == 0) {
        uint2 p;
        p.x = (uint_t)f2bf(a0) | ((uint_t)f2bf(a1) << 16);
        p.y = (uint_t)f2bf(a2) | ((uint_t)f2bf(a3) << 16);
        ((uint2*)agg_bf)[(size_t)node * 32 + sl] = p;
    }
}

// ---------------- fused GRU cell: LDS-staged weights, 4 waves share one c0 slice ----------------
// block = (c0, chunk); stages 24KB of packed B-frags into LDS once, waves re-read
// per row-group via conflict-free ds_read_b128. Low VGPR -> high occupancy.
__global__ __launch_bounds__(256, 4) void k_gru(const ushort_t* __restrict__ agg_bf,
                                                const ushort_t* __restrict__ hbf_in,
                                                ushort_t* __restrict__ hbf_out,
                                                const ushort_t* __restrict__ wx_pk,
                                                const ushort_t* __restrict__ wh_pk,
                                                const float* __restrict__ b_ih,
                                                const float* __restrict__ b_hh) {
    __shared__ ushort_t wlds[24 * 512];   // frags 0..11 = BX, 12..23 = BH; frag f lane l at (f*512 + l*8)
    int t = threadIdx.x;
    int c0 = blockIdx.x & 7;
    int chunk = blockIdx.x >> 3;
    {
        const uint4* sx = (const uint4*)(wx_pk + (size_t)c0 * 12 * 512);
        const uint4* sh = (const uint4*)(wh_pk + (size_t)c0 * 12 * 512);
        uint4* d = (uint4*)wlds;
#pragma unroll
        for (int i = 0; i < 3; i++) {
            d[t + i * 256] = sx[t + i * 256];           // 768 uint4 = 12KB BX
            d[768 + t + i * 256] = sh[t + i * 256];     // 12KB BH
        }
    }
    __syncthreads();

    int w = t >> 6, l = t & 63;
    int lr = l & 15, lg = l >> 4;
    int c = c0 * 16 + lr;
    float bxr = b_ih[c], bxz = b_ih[128 + c], bxn = b_ih[256 + c];
    float bhr = b_hh[c], bhz = b_hh[128 + c], bhn = b_hh[256 + c];
    const bf16x8* BL = (const bf16x8*)wlds;    // frag f, lane l -> BL[f*64 + l]

    for (int it = 0; it < G_RG; it++) {
        int rg = (chunk * 4 + w) * G_RG + it;
        if (rg >= NRG) break;
        int n0 = rg * 16;
        const short* ap = (const short*)agg_bf + (size_t)(n0 + lr) * CC + lg * 8;
        const short* hp = (const short*)hbf_in + (size_t)(n0 + lr) * CC + lg * 8;
        bf16x8 a[4], hf[4];
#pragma unroll
        for (int s = 0; s < 4; s++) {
            a[s] = *(const bf16x8*)(ap + s * 32);
            hf[s] = *(const bf16x8*)(hp + s * 32);
        }
        float hv[4];
#pragma unroll
        for (int j = 0; j < 4; j++)
            hv[j] = bf2f(hbf_in[(size_t)(n0 + lg * 4 + j) * CC + c]);

        f32x4 r0 = {0.f,0.f,0.f,0.f}, r1 = {0.f,0.f,0.f,0.f}, r2 = {0.f,0.f,0.f,0.f};
        f32x4 r3 = {0.f,0.f,0.f,0.f}, r4 = {0.f,0.f,0.f,0.f}, r5 = {0.f,0.f,0.f,0.f};
#pragma unroll
        for (int s = 0; s < 4; s++) {
            r0 = __builtin_amdgcn_mfma_f32_16x16x32_bf16(a[s], BL[s * 64 + l], r0, 0, 0, 0);
            r1 = __builtin_amdgcn_mfma_f32_16x16x32_bf16(a[s], BL[(4 + s) * 64 + l], r1, 0, 0, 0);
            r2 = __builtin_amdgcn_mfma_f32_16x16x32_bf16(a[s], BL[(8 + s) * 64 + l], r2, 0, 0, 0);
            r3 = __builtin_amdgcn_mfma_f32_16x16x32_bf16(hf[s], BL[(12 + s) * 64 + l], r3, 0, 0, 0);
            r4 = __builtin_amdgcn_mfma_f32_16x16x32_bf16(hf[s], BL[(16 + s) * 64 + l], r4, 0, 0, 0);
            r5 = __builtin_amdgcn_mfma_f32_16x16x32_bf16(hf[s], BL[(20 + s) * 64 + l], r5, 0, 0, 0);
        }
#pragma unroll
        for (int j = 0; j < 4; j++) {
            size_t row = (size_t)(n0 + lg * 4 + j);
            float rg_ = fsig(r0[j] + bxr + r3[j] + bhr);
            float zg = fsig(r1[j] + bxz + r4[j] + bhz);
            float ng = ftanh(r2[j] + bxn + rg_ * (r5[j] + bhn));
            float hn2 = (1.f - zg) * ng + zg * hv[j];
            hbf_out[row * CC + c] = f2bf(hn2);
        }
    }
}

// ---------------- MFMA MLP + log_softmax: wave per 16 rows ----------------
__global__ __launch_bounds__(256, 2) void k_mlp(const ushort_t* __restrict__ hbf,
                                                const ushort_t* __restrict__ wm_pk,
                                                const float* __restrict__ b0,
                                                const float* __restrict__ b1,
                                                const float* __restrict__ b2,
                                                const float* __restrict__ b3,
                                                float* __restrict__ out) {
    __shared__ short vt[4][16][40];
    __shared__ float yt[4][16][8];
    int wid = (blockIdx.x * 256 + threadIdx.x) >> 6;
    int wq = threadIdx.x >> 6;
    int l = threadIdx.x & 63;
    int lr = l & 15, lg = l >> 4;

    bf16x8 W0[2][4], W1[2], W2[2], W3;
    {
        const bf16x8* pw = (const bf16x8*)wm_pk;
#pragma unroll
        for (int c0 = 0; c0 < 2; c0++)
#pragma unroll
            for (int s = 0; s < 4; s++) W0[c0][s] = pw[(c0 * 4 + s) * 64 + l];
#pragma unroll
        for (int c0 = 0; c0 < 2; c0++) {
            W1[c0] = pw[512 + c0 * 64 + l];
            W2[c0] = pw[640 + c0 * 64 + l];
        }
        W3 = pw[768 + l];
    }
    float b0v[2] = {b0[lr], b0[16 + lr]};
    float b1v[2] = {b1[lr], b1[16 + lr]};
    float b2v[2] = {b2[lr], b2[16 + lr]};
    float b3v = (lr < 7) ? b3[lr] : 0.f;

    if (wid >= NRG) return;
    int n0 = wid * 16;

    bf16x8 a[4];
    {
        const short* ap = (const short*)hbf + (size_t)(n0 + lr) * CC + lg * 8;
#pragma unroll
        for (int s = 0; s < 4; s++) a[s] = *(const bf16x8*)(ap + s * 32);
    }
#pragma unroll
    for (int c0 = 0; c0 < 2; c0++) {
        f32x4 acc = {0.f, 0.f, 0.f, 0.f};
#pragma unroll
        for (int s = 0; s < 4; s++)
            acc = __builtin_amdgcn_mfma_f32_16x16x32_bf16(a[s], W0[c0][s], acc, 0, 0, 0);
#pragma unroll
        for (int j = 0; j < 4; j++)
            vt[wq][lg * 4 + j][c0 * 16 + lr] = (short)f2bf(ftanh(acc[j] + b0v[c0]));
    }
    {
        bf16x8 av = *(const bf16x8*)&vt[wq][lr][lg * 8];
        f32x4 acc[2];
#pragma unroll
        for (int c0 = 0; c0 < 2; c0++) {
            f32x4 z = {0.f, 0.f, 0.f, 0.f};
            acc[c0] = __builtin_amdgcn_mfma_f32_16x16x32_bf16(av, W1[c0], z, 0, 0, 0);
        }
#pragma unroll
        for (int c0 = 0; c0 < 2; c0++)
#pragma unroll
            for (int j = 0; j < 4; j++)
                vt[wq][lg * 4 + j][c0 * 16 + lr] = (short)f2bf(ftanh(acc[c0][j] + b1v[c0]));
    }
    {
        bf16x8 av = *(const bf16x8*)&vt[wq][lr][lg * 8];
        f32x4 acc[2];
#pragma unroll
        for (int c0 = 0; c0 < 2; c0++) {
            f32x4 z = {0.f, 0.f, 0.f, 0.f};
            acc[c0] = __builtin_amdgcn_mfma_f32_16x16x32_bf16(av, W2[c0], z, 0, 0, 0);
        }
#pragma unroll
        for (int c0 = 0; c0 < 2; c0++)
#pragma unroll
            for (int j = 0; j < 4; j++)
                vt[wq][lg * 4 + j][c0 * 16 + lr] = (short)f2bf(ftanh(acc[c0][j] + b2v[c0]));
    }
    {
        bf16x8 av = *(const bf16x8*)&vt[wq][lr][lg * 8];
        f32x4 z = {0.f, 0.f, 0.f, 0.f};
        f32x4 acc = __builtin_amdgcn_mfma_f32_16x16x32_bf16(av, W3, z, 0, 0, 0);
        if (lr < 7) {
#pragma unroll
            for (int j = 0; j < 4; j++) yt[wq][lg * 4 + j][lr] = acc[j] + b3v;
        }
    }
    __builtin_amdgcn_s_waitcnt(0);
    if (l < 16) {
        float y[7];
#pragma unroll
        for (int j = 0; j < 7; j++) y[j] = yt[wq][l][j];
        float mx = y[0];
#pragma unroll
        for (int j = 1; j < 7; j++) mx = fmaxf(mx, y[j]);
        float se = 0.f;
#pragma unroll
        for (int j = 0; j < 7; j++) se += expf(y[j] - mx);
        float lse = mx + logf(se);
#pragma unroll
        for (int j = 0; j < 7; j++) out[(size_t)(n0 + l) * 7 + j] = y[j] - lse;
    }
}

extern "C" void kernel_launch(void* const* d_in, const int* in_sizes, int n_in,
                              void* d_out, int out_size, void* d_ws, size_t ws_size,
                              hipStream_t stream) {
    const float* x   = (const float*)d_in[0];
    const int*   ei  = (const int*)d_in[1];
    const float* ew  = (const float*)d_in[2];
    const float* cw  = (const float*)d_in[3];
    const float* wih = (const float*)d_in[4];
    const float* whh = (const float*)d_in[5];
    const float* bih = (const float*)d_in[6];
    const float* bhh = (const float*)d_in[7];
    const float* w0 = (const float*)d_in[8];
    const float* b0 = (const float*)d_in[9];
    const float* w1 = (const float*)d_in[10];
    const float* b1 = (const float*)d_in[11];
    const float* w2 = (const float*)d_in[12];
    const float* b2 = (const float*)d_in[13];
    const float* w3 = (const float*)d_in[14];
    const float* b3 = (const float*)d_in[15];
    float* out = (float*)d_out;

    ushort_t* hbf0  = (ushort_t*)d_ws;                 // NN*CC
    ushort_t* hbf1  = hbf0 + (size_t)NN * CC;
    ushort_t* m_bf  = hbf1 + (size_t)NN * CC;
    ushort_t* agg_bf= m_bf + (size_t)NN * CC;
    ushort_t* wx_pk = agg_bf + (size_t)NN * CC;        // 49152
    ushort_t* wh_pk = wx_pk + 3 * CC * CC;
    ushort_t* cw_pk = wh_pk + 3 * CC * CC;
    ushort_t* wm_pk = cw_pk + 3 * CC * CC;             // 6656
    uint2*    e_pair= (uint2*)(wm_pk + 6656);          // NE uint2
    int*      off   = (int*)(e_pair + NE);             // NN+1 (block-local prefix; off[NN] absolute)
    int*      deg   = off + (NN + 1);                  // NN   } contiguous: zeroed together
    int*      cnt   = deg + NN;                        // NN   }
    int*      bsum  = cnt + NN;                        // SCAN_B
    int*      bofs  = bsum + SCAN_B;                   // SCAN_B

    const int* src = ei;
    const int* dst = ei + NE;

    // merged prep (cvt + packs + deg/cnt zero)
    k_prep<<<7243, 256, 0, stream>>>(x, hbf0, wih, whh, cw, w0, w1, w2, w3,
                                     wx_pk, wh_pk, cw_pk, wm_pk, deg);

    // CSR build (final offsets reconstructed as off[i] + bofs[i>>8])
    k_count<<<(NE / 4 + 255) / 256, 256, 0, stream>>>(dst, deg);
    k_scan1<<<SCAN_B, 256, 0, stream>>>(deg, off, bsum);
    k_scan2<<<1, 256, 0, stream>>>(bsum, bofs, off);
    k_fill<<<(NE + 255) / 256, 256, 0, stream>>>(src, dst, ew, off, bofs, cnt, e_pair);

    const int conv_waves = 4 * ((NRG + C_RG - 1) / C_RG);
    const int conv_blk = (conv_waves + 3) / 4;
    const int gru_blk = 8 * ((NRG + 4 * G_RG - 1) / (4 * G_RG));   // (c0, chunk) blocks

    ushort_t* hin = hbf0;
    ushort_t* hout = hbf1;
    for (int l = 0; l < NL; l++) {
        k_conv<<<conv_blk, 256, 0, stream>>>(hin, cw_pk + (size_t)l * CC * CC, m_bf);
        k_agg<<<(NN + 3) / 4, 256, 0, stream>>>(off, bofs, e_pair, m_bf, agg_bf);
        k_gru<<<gru_blk, 256, 0, stream>>>(agg_bf, hin, hout, wx_pk, wh_pk, bih, bhh);
        ushort_t* tmp = hin; hin = hout; hout = tmp;
    }
    k_mlp<<<(NRG + 3) / 4, 256, 0, stream>>>(hin, wm_pk, b0, b1, b2, b3, out);
}

// Round 14
// 293.953 us; speedup vs baseline: 1.0921x; 1.0921x over previous
//
#include <hip/hip_runtime.h>
#include <hip/hip_bf16.h>
#include <math.h>

#define NN 50000
#define NE 600000
#define CC 128
#define NL 3
#define NRG (NN / 16)      // 3125 row-groups
#define C_RG 4             // row-groups per conv wave
#define G_RG 4             // row-groups per gru wave
#define NCHUNK 196         // ceil(NRG/16): gru chunk = 16 row-groups (block of 4 waves x G_RG)
#define SCAN_B 196         // ceil(NN/256)

typedef __attribute__((ext_vector_type(8))) short bf16x8;
typedef __attribute__((ext_vector_type(4))) float f32x4;
typedef unsigned short ushort_t;
typedef unsigned int uint_t;

__device__ inline ushort_t f2bf(float f) {
    __hip_bfloat16 b = __float2bfloat16(f);
    return *reinterpret_cast<ushort_t*>(&b);
}
__device__ inline float bf2f(ushort_t u) {
    return __uint_as_float(((uint_t)u) << 16);
}
__device__ inline float fsig(float x) {
    return __builtin_amdgcn_rcpf(1.f + __builtin_amdgcn_exp2f(-1.44269504f * x));
}
__device__ inline float ftanh(float x) {
    float e = __builtin_amdgcn_exp2f(2.88539008f * fabsf(x));
    float t = 1.f - 2.f * __builtin_amdgcn_rcpf(e + 1.f);
    return copysignf(t, x);
}

// ---------------- merged prep: cvt + all weight packs + deg/cnt zero ----------------
__global__ __launch_bounds__(256) void k_prep(const float* __restrict__ x,
                                              ushort_t* __restrict__ h_bf,
                                              const float* __restrict__ wih,
                                              const float* __restrict__ whh,
                                              const float* __restrict__ cw,
                                              const float* __restrict__ w0,
                                              const float* __restrict__ w1,
                                              const float* __restrict__ w2,
                                              const float* __restrict__ w3,
                                              ushort_t* __restrict__ wx_pk,
                                              ushort_t* __restrict__ wh_pk,
                                              ushort_t* __restrict__ cw_pk,
                                              ushort_t* __restrict__ wm_pk,
                                              int* __restrict__ degcnt) {
    int bid = blockIdx.x;
    int t = threadIdx.x;
    if (bid < 6250) {
        size_t i = (size_t)bid * 256 + t;
        float4 v = ((const float4*)x)[i];
        ushort4 u;
        u.x = f2bf(v.x); u.y = f2bf(v.y); u.z = f2bf(v.z); u.w = f2bf(v.w);
        ((ushort4*)h_bf)[i] = u;
        return;
    }
    int bb = bid - 6250;
    if (bb < 384) {
        const float* W = (bb < 192) ? wih : whh;
        ushort_t* pk = (bb < 192) ? wx_pk : wh_pk;
        int tid = ((bb < 192) ? bb : bb - 192) * 256 + t;    // 49152
        int e = tid & 7;
        int l = (tid >> 3) & 63;
        int s = (tid >> 9) & 3;
        int rest = tid >> 11;                // c0*3+g
        int g = rest % 3, c0 = rest / 3;
        int row = g * 128 + c0 * 16 + (l & 15);
        int col = s * 32 + (l >> 4) * 8 + e;
        pk[tid] = f2bf(W[row * 128 + col]);
        return;
    }
    bb -= 384;
    if (bb < 192) {
        int tid = bb * 256 + t;              // 49152
        int e = tid & 7;
        int l = (tid >> 3) & 63;
        int s = (tid >> 9) & 3;
        int rest = tid >> 11;                // layer*8 + c0
        int c0 = rest & 7, layer = rest >> 3;
        int c = c0 * 16 + (l & 15);
        int k = s * 32 + (l >> 4) * 8 + e;
        cw_pk[tid] = f2bf(cw[layer * 16384 + k * 128 + c]);
        return;
    }
    bb -= 192;
    if (bb < 26) {
        int tid = bb * 256 + t;              // 6656
        if (tid >= 6656) return;
        int e = tid & 7;
        int l = (tid >> 3) & 63;
        int lr = l & 15, lg = l >> 4;
        if (tid < 4096) {
            int s = (tid >> 9) & 3;
            int c0 = tid >> 11;
            wm_pk[tid] = f2bf(w0[(c0 * 16 + lr) * 128 + s * 32 + lg * 8 + e]);
        } else if (tid < 5120) {
            int c0 = (tid - 4096) >> 9;
            wm_pk[tid] = f2bf(w1[(c0 * 16 + lr) * 32 + lg * 8 + e]);
        } else if (tid < 6144) {
            int c0 = (tid - 5120) >> 9;
            wm_pk[tid] = f2bf(w2[(c0 * 16 + lr) * 32 + lg * 8 + e]);
        } else {
            wm_pk[tid] = (lr < 7) ? f2bf(w3[lr * 32 + lg * 8 + e]) : (ushort_t)0;
        }
        return;
    }
    bb -= 26;
    {   // zero deg+cnt: 391 blocks over 2*NN ints
        int i = bb * 256 + t;
        if (i < 2 * NN) degcnt[i] = 0;
    }
}

// ---------------- count: int4-vectorized histogram ----------------
__global__ __launch_bounds__(256) void k_count(const int* __restrict__ dst,
                                               int* __restrict__ deg) {
    int c = blockIdx.x * 256 + threadIdx.x;      // over NE/4 int4
    if (c >= NE / 4) return;
    int4 d4 = ((const int4*)dst)[c];
    atomicAdd(&deg[d4.x], 1);
    atomicAdd(&deg[d4.y], 1);
    atomicAdd(&deg[d4.z], 1);
    atomicAdd(&deg[d4.w], 1);
}

__global__ __launch_bounds__(256) void k_scan1(const int* __restrict__ deg,
                                               int* __restrict__ off,
                                               int* __restrict__ bsum) {
    __shared__ int sm[256];
    int t = threadIdx.x, i = blockIdx.x * 256 + t;
    int v = (i < NN) ? deg[i] : 0;
    sm[t] = v;
    __syncthreads();
#pragma unroll
    for (int ofs = 1; ofs < 256; ofs <<= 1) {
        int u = (t >= ofs) ? sm[t - ofs] : 0;
        __syncthreads();
        sm[t] += u;
        __syncthreads();
    }
    if (i < NN) off[i] = sm[t] - v;
    if (t == 255) bsum[blockIdx.x] = sm[255];
}

__global__ __launch_bounds__(256) void k_scan2(const int* __restrict__ bsum,
                                               int* __restrict__ bofs,
                                               int* __restrict__ off) {
    __shared__ int sm[256];
    int t = threadIdx.x;
    int v = (t < SCAN_B) ? bsum[t] : 0;
    sm[t] = v;
    __syncthreads();
#pragma unroll
    for (int ofs = 1; ofs < 256; ofs <<= 1) {
        int u = (t >= ofs) ? sm[t - ofs] : 0;
        __syncthreads();
        sm[t] += u;
        __syncthreads();
    }
    if (t < SCAN_B) bofs[t] = sm[t] - v;
    if (t == 255) off[NN] = sm[255];
}

// ---------------- fill: atomic per-node cursor, one 8B packed store per edge ----------------
__global__ __launch_bounds__(256) void k_fill(const int* __restrict__ src,
                                              const int* __restrict__ dst,
                                              const float* __restrict__ ew,
                                              const int* __restrict__ off_p,
                                              const int* __restrict__ bofs,
                                              int* __restrict__ cnt,
                                              uint2* __restrict__ e_pair) {
    int e = blockIdx.x * 256 + threadIdx.x;
    if (e >= NE) return;
    int d = dst[e];
    int p = off_p[d] + bofs[d >> 8] + atomicAdd(&cnt[d], 1);
    uint2 pr;
    pr.x = (uint_t)src[e];
    pr.y = __float_as_uint(ew[e]);
    e_pair[p] = pr;
}

// ---------------- m_bf = bf16( h_bf @ W ), weight-resident waves ----------------
__global__ __launch_bounds__(256, 2) void k_conv(const ushort_t* __restrict__ h_bf,
                                                 const ushort_t* __restrict__ cw_pk,
                                                 ushort_t* __restrict__ m_bf) {
    int wid = (blockIdx.x * 256 + threadIdx.x) >> 6;
    int l = threadIdx.x & 63;
    int lr = l & 15, lg = l >> 4;
    int c0g = wid & 3;
    int chunk = wid >> 2;

    bf16x8 B[2][4];
    {
        const bf16x8* pw = (const bf16x8*)cw_pk;
#pragma unroll
        for (int p = 0; p < 2; p++)
#pragma unroll
            for (int s = 0; s < 4; s++)
                B[p][s] = pw[(size_t)(((c0g + 4 * p) * 4 + s) * 64) + l];
    }
    int c_lo = c0g * 16 + lr;

    for (int it = 0; it < C_RG; it++) {
        int rg = chunk * C_RG + it;
        if (rg >= NRG) break;
        int n0 = rg * 16;
        const short* ap = (const short*)h_bf + (size_t)(n0 + lr) * CC + lg * 8;
        bf16x8 a[4];
#pragma unroll
        for (int s = 0; s < 4; s++) a[s] = *(const bf16x8*)(ap + s * 32);
        f32x4 acc0 = {0.f,0.f,0.f,0.f}, acc1 = {0.f,0.f,0.f,0.f};
#pragma unroll
        for (int s = 0; s < 4; s++) {
            acc0 = __builtin_amdgcn_mfma_f32_16x16x32_bf16(a[s], B[0][s], acc0, 0, 0, 0);
            acc1 = __builtin_amdgcn_mfma_f32_16x16x32_bf16(a[s], B[1][s], acc1, 0, 0, 0);
        }
#pragma unroll
        for (int j = 0; j < 4; j++) {
            size_t row = (size_t)(n0 + lg * 4 + j) * CC;
            m_bf[row + c_lo] = f2bf(acc0[j]);
            m_bf[row + c_lo + 64] = f2bf(acc1[j]);
        }
    }
}

// ---------------- agg: halves over edges, 8 gathers in flight ----------------
__global__ __launch_bounds__(256) void k_agg(const int* __restrict__ off_p,
                                             const int* __restrict__ bofs,
                                             const uint2* __restrict__ e_pair,
                                             const ushort_t* __restrict__ m_bf,
                                             ushort_t* __restrict__ agg_bf) {
    int node = blockIdx.x * 4 + (threadIdx.x >> 6);
    int l = threadIdx.x & 63;
    int half = l >> 5, sl = l & 31;
    if (node >= NN) return;
    int b = off_p[node] + bofs[node >> 8];
    int e = (node == NN - 1) ? off_p[NN]
                             : off_p[node + 1] + bofs[(node + 1) >> 8];
    const uint2* m2 = (const uint2*)m_bf;   // row = 32 x uint2
    float a0 = 0.f, a1 = 0.f, a2 = 0.f, a3 = 0.f;
    int i = b;
    for (; i + 8 <= e; i += 8) {
        uint2 p0 = e_pair[i + half];
        uint2 p1 = e_pair[i + 2 + half];
        uint2 p2 = e_pair[i + 4 + half];
        uint2 p3 = e_pair[i + 6 + half];
        uint2 v0 = m2[(size_t)p0.x * 32 + sl];
        uint2 v1 = m2[(size_t)p1.x * 32 + sl];
        uint2 v2 = m2[(size_t)p2.x * 32 + sl];
        uint2 v3 = m2[(size_t)p3.x * 32 + sl];
        float w0 = __uint_as_float(p0.y), w1 = __uint_as_float(p1.y);
        float w2 = __uint_as_float(p2.y), w3 = __uint_as_float(p3.y);
        a0 += w0 * bf2f((ushort_t)(v0.x & 0xffffu)) + w1 * bf2f((ushort_t)(v1.x & 0xffffu))
            + w2 * bf2f((ushort_t)(v2.x & 0xffffu)) + w3 * bf2f((ushort_t)(v3.x & 0xffffu));
        a1 += w0 * bf2f((ushort_t)(v0.x >> 16))     + w1 * bf2f((ushort_t)(v1.x >> 16))
            + w2 * bf2f((ushort_t)(v2.x >> 16))     + w3 * bf2f((ushort_t)(v3.x >> 16));
        a2 += w0 * bf2f((ushort_t)(v0.y & 0xffffu)) + w1 * bf2f((ushort_t)(v1.y & 0xffffu))
            + w2 * bf2f((ushort_t)(v2.y & 0xffffu)) + w3 * bf2f((ushort_t)(v3.y & 0xffffu));
        a3 += w0 * bf2f((ushort_t)(v0.y >> 16))     + w1 * bf2f((ushort_t)(v1.y >> 16))
            + w2 * bf2f((ushort_t)(v2.y >> 16))     + w3 * bf2f((ushort_t)(v3.y >> 16));
    }
    for (; i + 4 <= e; i += 4) {
        uint2 p0 = e_pair[i + half];
        uint2 p1 = e_pair[i + 2 + half];
        uint2 v0 = m2[(size_t)p0.x * 32 + sl];
        uint2 v1 = m2[(size_t)p1.x * 32 + sl];
        float w0 = __uint_as_float(p0.y), w1 = __uint_as_float(p1.y);
        a0 += w0 * bf2f((ushort_t)(v0.x & 0xffffu)) + w1 * bf2f((ushort_t)(v1.x & 0xffffu));
        a1 += w0 * bf2f((ushort_t)(v0.x >> 16))     + w1 * bf2f((ushort_t)(v1.x >> 16));
        a2 += w0 * bf2f((ushort_t)(v0.y & 0xffffu)) + w1 * bf2f((ushort_t)(v1.y & 0xffffu));
        a3 += w0 * bf2f((ushort_t)(v0.y >> 16))     + w1 * bf2f((ushort_t)(v1.y >> 16));
    }
    for (; i < e; i += 2) {
        int idx = i + half;
        uint2 pr = (idx < e) ? e_pair[idx] : make_uint2(0u, 0u);
        uint2 v = m2[(size_t)pr.x * 32 + sl];
        float w = __uint_as_float(pr.y);
        a0 += w * bf2f((ushort_t)(v.x & 0xffffu));
        a1 += w * bf2f((ushort_t)(v.x >> 16));
        a2 += w * bf2f((ushort_t)(v.y & 0xffffu));
        a3 += w * bf2f((ushort_t)(v.y >> 16));
    }
    a0 += __shfl_xor(a0, 32);
    a1 += __shfl_xor(a1, 32);
    a2 += __shfl_xor(a2, 32);
    a3 += __shfl_xor(a3, 32);
    if (half == 0) {
        uint2 p;
        p.x = (uint_t)f2bf(a0) | ((uint_t)f2bf(a1) << 16);
        p.y = (uint_t)f2bf(a2) | ((uint_t)f2bf(a3) << 16);
        ((uint2*)agg_bf)[(size_t)node * 32 + sl] = p;
    }
}

// ---------------- fused GRU cell: LDS-staged weights + XCD-aware chunk mapping ----------------
// All 8 c0-blocks of one chunk land on the SAME XCD (bid % 8 == chunk % 8), so the
// chunk's agg/hbf rows are fetched into one L2, not eight.
__global__ __launch_bounds__(256, 4) void k_gru(const ushort_t* __restrict__ agg_bf,
                                                const ushort_t* __restrict__ hbf_in,
                                                ushort_t* __restrict__ hbf_out,
                                                const ushort_t* __restrict__ wx_pk,
                                                const ushort_t* __restrict__ wh_pk,
                                                const float* __restrict__ b_ih,
                                                const float* __restrict__ b_hh) {
    __shared__ ushort_t wlds[24 * 512];   // frags 0..11 = BX, 12..23 = BH
    int t = threadIdx.x;
    int bid = blockIdx.x;
    int xcd = bid & 7;
    int j = bid >> 3;
    int c0 = j & 7;
    int chunk = (j >> 3) * 8 + xcd;       // same chunk -> same XCD
    if (chunk >= NCHUNK) return;
    {
        const uint4* sx = (const uint4*)(wx_pk + (size_t)c0 * 12 * 512);
        const uint4* sh = (const uint4*)(wh_pk + (size_t)c0 * 12 * 512);
        uint4* d = (uint4*)wlds;
#pragma unroll
        for (int i = 0; i < 3; i++) {
            d[t + i * 256] = sx[t + i * 256];           // 12KB BX
            d[768 + t + i * 256] = sh[t + i * 256];     // 12KB BH
        }
    }
    __syncthreads();

    int w = t >> 6, l = t & 63;
    int lr = l & 15, lg = l >> 4;
    int c = c0 * 16 + lr;
    float bxr = b_ih[c], bxz = b_ih[128 + c], bxn = b_ih[256 + c];
    float bhr = b_hh[c], bhz = b_hh[128 + c], bhn = b_hh[256 + c];
    const bf16x8* BL = (const bf16x8*)wlds;    // frag f, lane l -> BL[f*64 + l]

    for (int it = 0; it < G_RG; it++) {
        int rg = (chunk * 4 + w) * G_RG + it;
        if (rg >= NRG) break;
        int n0 = rg * 16;
        const short* ap = (const short*)agg_bf + (size_t)(n0 + lr) * CC + lg * 8;
        const short* hp = (const short*)hbf_in + (size_t)(n0 + lr) * CC + lg * 8;
        bf16x8 a[4], hf[4];
#pragma unroll
        for (int s = 0; s < 4; s++) {
            a[s] = *(const bf16x8*)(ap + s * 32);
            hf[s] = *(const bf16x8*)(hp + s * 32);
        }
        float hv[4];
#pragma unroll
        for (int j2 = 0; j2 < 4; j2++)
            hv[j2] = bf2f(hbf_in[(size_t)(n0 + lg * 4 + j2) * CC + c]);

        f32x4 r0 = {0.f,0.f,0.f,0.f}, r1 = {0.f,0.f,0.f,0.f}, r2 = {0.f,0.f,0.f,0.f};
        f32x4 r3 = {0.f,0.f,0.f,0.f}, r4 = {0.f,0.f,0.f,0.f}, r5 = {0.f,0.f,0.f,0.f};
#pragma unroll
        for (int s = 0; s < 4; s++) {
            r0 = __builtin_amdgcn_mfma_f32_16x16x32_bf16(a[s], BL[s * 64 + l], r0, 0, 0, 0);
            r1 = __builtin_amdgcn_mfma_f32_16x16x32_bf16(a[s], BL[(4 + s) * 64 + l], r1, 0, 0, 0);
            r2 = __builtin_amdgcn_mfma_f32_16x16x32_bf16(a[s], BL[(8 + s) * 64 + l], r2, 0, 0, 0);
            r3 = __builtin_amdgcn_mfma_f32_16x16x32_bf16(hf[s], BL[(12 + s) * 64 + l], r3, 0, 0, 0);
            r4 = __builtin_amdgcn_mfma_f32_16x16x32_bf16(hf[s], BL[(16 + s) * 64 + l], r4, 0, 0, 0);
            r5 = __builtin_amdgcn_mfma_f32_16x16x32_bf16(hf[s], BL[(20 + s) * 64 + l], r5, 0, 0, 0);
        }
#pragma unroll
        for (int j2 = 0; j2 < 4; j2++) {
            size_t row = (size_t)(n0 + lg * 4 + j2);
            float rg_ = fsig(r0[j2] + bxr + r3[j2] + bhr);
            float zg = fsig(r1[j2] + bxz + r4[j2] + bhz);
            float ng = ftanh(r2[j2] + bxn + rg_ * (r5[j2] + bhn));
            float hn2 = (1.f - zg) * ng + zg * hv[j2];
            hbf_out[row * CC + c] = f2bf(hn2);
        }
    }
}

// ---------------- MFMA MLP + log_softmax: wave per 16 rows ----------------
__global__ __launch_bounds__(256, 2) void k_mlp(const ushort_t* __restrict__ hbf,
                                                const ushort_t* __restrict__ wm_pk,
                                                const float* __restrict__ b0,
                                                const float* __restrict__ b1,
                                                const float* __restrict__ b2,
                                                const float* __restrict__ b3,
                                                float* __restrict__ out) {
    __shared__ short vt[4][16][40];
    __shared__ float yt[4][16][8];
    int wid = (blockIdx.x * 256 + threadIdx.x) >> 6;
    int wq = threadIdx.x >> 6;
    int l = threadIdx.x & 63;
    int lr = l & 15, lg = l >> 4;

    bf16x8 W0[2][4], W1[2], W2[2], W3;
    {
        const bf16x8* pw = (const bf16x8*)wm_pk;
#pragma unroll
        for (int c0 = 0; c0 < 2; c0++)
#pragma unroll
            for (int s = 0; s < 4; s++) W0[c0][s] = pw[(c0 * 4 + s) * 64 + l];
#pragma unroll
        for (int c0 = 0; c0 < 2; c0++) {
            W1[c0] = pw[512 + c0 * 64 + l];
            W2[c0] = pw[640 + c0 * 64 + l];
        }
        W3 = pw[768 + l];
    }
    float b0v[2] = {b0[lr], b0[16 + lr]};
    float b1v[2] = {b1[lr], b1[16 + lr]};
    float b2v[2] = {b2[lr], b2[16 + lr]};
    float b3v = (lr < 7) ? b3[lr] : 0.f;

    if (wid >= NRG) return;
    int n0 = wid * 16;

    bf16x8 a[4];
    {
        const short* ap = (const short*)hbf + (size_t)(n0 + lr) * CC + lg * 8;
#pragma unroll
        for (int s = 0; s < 4; s++) a[s] = *(const bf16x8*)(ap + s * 32);
    }
#pragma unroll
    for (int c0 = 0; c0 < 2; c0++) {
        f32x4 acc = {0.f, 0.f, 0.f, 0.f};
#pragma unroll
        for (int s = 0; s < 4; s++)
            acc = __builtin_amdgcn_mfma_f32_16x16x32_bf16(a[s], W0[c0][s], acc, 0, 0, 0);
#pragma unroll
        for (int j = 0; j < 4; j++)
            vt[wq][lg * 4 + j][c0 * 16 + lr] = (short)f2bf(ftanh(acc[j] + b0v[c0]));
    }
    {
        bf16x8 av = *(const bf16x8*)&vt[wq][lr][lg * 8];
        f32x4 acc[2];
#pragma unroll
        for (int c0 = 0; c0 < 2; c0++) {
            f32x4 z = {0.f, 0.f, 0.f, 0.f};
            acc[c0] = __builtin_amdgcn_mfma_f32_16x16x32_bf16(av, W1[c0], z, 0, 0, 0);
        }
#pragma unroll
        for (int c0 = 0; c0 < 2; c0++)
#pragma unroll
            for (int j = 0; j < 4; j++)
                vt[wq][lg * 4 + j][c0 * 16 + lr] = (short)f2bf(ftanh(acc[c0][j] + b1v[c0]));
    }
    {
        bf16x8 av = *(const bf16x8*)&vt[wq][lr][lg * 8];
        f32x4 acc[2];
#pragma unroll
        for (int c0 = 0; c0 < 2; c0++) {
            f32x4 z = {0.f, 0.f, 0.f, 0.f};
            acc[c0] = __builtin_amdgcn_mfma_f32_16x16x32_bf16(av, W2[c0], z, 0, 0, 0);
        }
#pragma unroll
        for (int c0 = 0; c0 < 2; c0++)
#pragma unroll
            for (int j = 0; j < 4; j++)
                vt[wq][lg * 4 + j][c0 * 16 + lr] = (short)f2bf(ftanh(acc[c0][j] + b2v[c0]));
    }
    {
        bf16x8 av = *(const bf16x8*)&vt[wq][lr][lg * 8];
        f32x4 z = {0.f, 0.f, 0.f, 0.f};
        f32x4 acc = __builtin_amdgcn_mfma_f32_16x16x32_bf16(av, W3, z, 0, 0, 0);
        if (lr < 7) {
#pragma unroll
            for (int j = 0; j < 4; j++) yt[wq][lg * 4 + j][lr] = acc[j] + b3v;
        }
    }
    __builtin_amdgcn_s_waitcnt(0);
    if (l < 16) {
        float y[7];
#pragma unroll
        for (int j = 0; j < 7; j++) y[j] = yt[wq][l][j];
        float mx = y[0];
#pragma unroll
        for (int j = 1; j < 7; j++) mx = fmaxf(mx, y[j]);
        float se = 0.f;
#pragma unroll
        for (int j = 0; j < 7; j++) se += expf(y[j] - mx);
        float lse = mx + logf(se);
#pragma unroll
        for (int j = 0; j < 7; j++) out[(size_t)(n0 + l) * 7 + j] = y[j] - lse;
    }
}

extern "C" void kernel_launch(void* const* d_in, const int* in_sizes, int n_in,
                              void* d_out, int out_size, void* d_ws, size_t ws_size,
                              hipStream_t stream) {
    const float* x   = (const float*)d_in[0];
    const int*   ei  = (const int*)d_in[1];
    const float* ew  = (const float*)d_in[2];
    const float* cw  = (const float*)d_in[3];
    const float* wih = (const float*)d_in[4];
    const float* whh = (const float*)d_in[5];
    const float* bih = (const float*)d_in[6];
    const float* bhh = (const float*)d_in[7];
    const float* w0 = (const float*)d_in[8];
    const float* b0 = (const float*)d_in[9];
    const float* w1 = (const float*)d_in[10];
    const float* b1 = (const float*)d_in[11];
    const float* w2 = (const float*)d_in[12];
    const float* b2 = (const float*)d_in[13];
    const float* w3 = (const float*)d_in[14];
    const float* b3 = (const float*)d_in[15];
    float* out = (float*)d_out;

    ushort_t* hbf0  = (ushort_t*)d_ws;                 // NN*CC
    ushort_t* hbf1  = hbf0 + (size_t)NN * CC;
    ushort_t* m_bf  = hbf1 + (size_t)NN * CC;
    ushort_t* agg_bf= m_bf + (size_t)NN * CC;
    ushort_t* wx_pk = agg_bf + (size_t)NN * CC;        // 49152
    ushort_t* wh_pk = wx_pk + 3 * CC * CC;
    ushort_t* cw_pk = wh_pk + 3 * CC * CC;
    ushort_t* wm_pk = cw_pk + 3 * CC * CC;             // 6656
    uint2*    e_pair= (uint2*)(wm_pk + 6656);          // NE uint2
    int*      off   = (int*)(e_pair + NE);             // NN+1 (block-local prefix; off[NN] absolute)
    int*      deg   = off + (NN + 1);                  // NN   } contiguous: zeroed together
    int*      cnt   = deg + NN;                        // NN   }
    int*      bsum  = cnt + NN;                        // SCAN_B
    int*      bofs  = bsum + SCAN_B;                   // SCAN_B

    const int* src = ei;
    const int* dst = ei + NE;

    // merged prep (cvt + packs + deg/cnt zero)
    k_prep<<<7243, 256, 0, stream>>>(x, hbf0, wih, whh, cw, w0, w1, w2, w3,
                                     wx_pk, wh_pk, cw_pk, wm_pk, deg);

    // CSR build (final offsets reconstructed as off[i] + bofs[i>>8])
    k_count<<<(NE / 4 + 255) / 256, 256, 0, stream>>>(dst, deg);
    k_scan1<<<SCAN_B, 256, 0, stream>>>(deg, off, bsum);
    k_scan2<<<1, 256, 0, stream>>>(bsum, bofs, off);
    k_fill<<<(NE + 255) / 256, 256, 0, stream>>>(src, dst, ew, off, bofs, cnt, e_pair);

    const int conv_waves = 4 * ((NRG + C_RG - 1) / C_RG);
    const int conv_blk = (conv_waves + 3) / 4;
    const int gru_blk = 8 * (((NCHUNK + 7) / 8) * 8);   // 1600: bijective (c0, chunk) cover

    ushort_t* hin = hbf0;
    ushort_t* hout = hbf1;
    for (int l = 0; l < NL; l++) {
        k_conv<<<conv_blk, 256, 0, stream>>>(hin, cw_pk + (size_t)l * CC * CC, m_bf);
        k_agg<<<(NN + 3) / 4, 256, 0, stream>>>(off, bofs, e_pair, m_bf, agg_bf);
        k_gru<<<gru_blk, 256, 0, stream>>>(agg_bf, hin, hout, wx_pk, wh_pk, bih, bhh);
        ushort_t* tmp = hin; hin = hout; hout = tmp;
    }
    k_mlp<<<(NRG + 3) / 4, 256, 0, stream>>>(hin, wm_pk, b0, b1, b2, b3, out);
}